// Round 1
// baseline (1601.899 us; speedup 1.0000x reference)
//
#include <hip/hip_runtime.h>
#include <hip/hip_bf16.h>
#include <cstdio>

typedef __bf16 bf16;
typedef __bf16 bf16x8 __attribute__((ext_vector_type(8)));
typedef float f32x4 __attribute__((ext_vector_type(4)));

// ---------------------------------------------------------------------------
// Generic bf16 MFMA GEMM: C[M,N] = A[M,K] * B[N,K]^T + bias[N]
// Both operands K-major (row-major with K contiguous). 16x16x32 bf16 MFMA.
// Block = 256 threads = 4 waves (2x2). Wave tile = (BM/2)x(BN/2), built from
// 16x16 MFMA tiles: TM x TN per wave where TM=BM/32, TN=BN/32.
// CASTAB: operands are fp32 in global, cast to bf16 during LDS staging
//         (Klim = true K; k in [Klim, K) zero-filled).
// OUTBF16: store C as bf16, else fp32.
// NBOUND: predicate stores/bias on col < Nlim (for N=151 output).
// ---------------------------------------------------------------------------
template<int BM, int BN, bool CASTAB, bool OUTBF16, bool NBOUND>
__global__ __launch_bounds__(256)
void gemm_k(const void* __restrict__ Av, const void* __restrict__ Bv,
            void* __restrict__ Cv, const float* __restrict__ bias,
            int K, int Klim, int lda, int ldb, int ldc, int Nlim)
{
    constexpr int TM = BM / 32;          // 16-row subtiles per wave (M dim)
    constexpr int TN = BN / 32;          // 16-col subtiles per wave (N dim)
    constexpr int LDK = 40;              // 32 k-elems padded to 40 (bank spread)

    __shared__ __align__(16) bf16 As[BM * LDK];
    __shared__ __align__(16) bf16 Bs[BN * LDK];

    const int tid  = threadIdx.x;
    const int wave = tid >> 6;
    const int lane = tid & 63;
    const int lrow = lane & 15;
    const int q    = lane >> 4;

    const int rowbase = blockIdx.y * BM;
    const int colbase = blockIdx.x * BN;
    const int wr = (wave >> 1) * (BM / 2);
    const int wc = (wave & 1) * (BN / 2);

    f32x4 acc[TM][TN] = {};

    for (int kk = 0; kk < K; kk += 32) {
        __syncthreads();
        // ---- stage A tile: BM rows x 32 k, 8 bf16 per thread-chunk ----
        #pragma unroll
        for (int i = 0; i < BM / 64; ++i) {
            int chunk = tid + i * 256;
            int r  = chunk >> 2;
            int kc = (chunk & 3) * 8;
            int kg = kk + kc;
            bf16x8 v;
            if (CASTAB) {
                const float* src = (const float*)Av + (size_t)(rowbase + r) * lda + kg;
                if (kg + 8 <= Klim) {
                    float4 f0 = *(const float4*)(src);
                    float4 f1 = *(const float4*)(src + 4);
                    v[0]=(bf16)f0.x; v[1]=(bf16)f0.y; v[2]=(bf16)f0.z; v[3]=(bf16)f0.w;
                    v[4]=(bf16)f1.x; v[5]=(bf16)f1.y; v[6]=(bf16)f1.z; v[7]=(bf16)f1.w;
                } else {
                    #pragma unroll
                    for (int e = 0; e < 8; ++e)
                        v[e] = (kg + e < Klim) ? (bf16)src[e] : (bf16)0.f;
                }
            } else {
                v = *(const bf16x8*)((const bf16*)Av + (size_t)(rowbase + r) * lda + kg);
            }
            *(bf16x8*)&As[r * LDK + kc] = v;
        }
        // ---- stage B tile: BN rows x 32 k ----
        #pragma unroll
        for (int i = 0; i < BN / 64; ++i) {
            int chunk = tid + i * 256;
            int r  = chunk >> 2;
            int kc = (chunk & 3) * 8;
            int kg = kk + kc;
            bf16x8 v;
            if (CASTAB) {
                const float* src = (const float*)Bv + (size_t)(colbase + r) * ldb + kg;
                if (kg + 8 <= Klim) {
                    float4 f0 = *(const float4*)(src);
                    float4 f1 = *(const float4*)(src + 4);
                    v[0]=(bf16)f0.x; v[1]=(bf16)f0.y; v[2]=(bf16)f0.z; v[3]=(bf16)f0.w;
                    v[4]=(bf16)f1.x; v[5]=(bf16)f1.y; v[6]=(bf16)f1.z; v[7]=(bf16)f1.w;
                } else {
                    #pragma unroll
                    for (int e = 0; e < 8; ++e)
                        v[e] = (kg + e < Klim) ? (bf16)src[e] : (bf16)0.f;
                }
            } else {
                v = *(const bf16x8*)((const bf16*)Bv + (size_t)(colbase + r) * ldb + kg);
            }
            *(bf16x8*)&Bs[r * LDK + kc] = v;
        }
        __syncthreads();

        // ---- fragments + MFMA ----
        // A-frag: lane holds A[m = lane&15][k = q*8 + j]  (m89-verified layout)
        // B-frag: lane holds B^T row n = lane&15, same k range
        bf16x8 afr[TM], bfr[TN];
        #pragma unroll
        for (int m = 0; m < TM; ++m)
            afr[m] = *(const bf16x8*)&As[(wr + m * 16 + lrow) * LDK + q * 8];
        #pragma unroll
        for (int n = 0; n < TN; ++n)
            bfr[n] = *(const bf16x8*)&Bs[(wc + n * 16 + lrow) * LDK + q * 8];
        #pragma unroll
        for (int m = 0; m < TM; ++m)
            #pragma unroll
            for (int n = 0; n < TN; ++n)
                acc[m][n] = __builtin_amdgcn_mfma_f32_16x16x32_bf16(
                                afr[m], bfr[n], acc[m][n], 0, 0, 0);
    }

    // ---- epilogue: D[row=(q*4+reg)][col=lane&15] per 16x16 tile ----
    #pragma unroll
    for (int m = 0; m < TM; ++m) {
        #pragma unroll
        for (int n = 0; n < TN; ++n) {
            int gr0 = rowbase + wr + m * 16 + q * 4;
            int gc  = colbase + wc + n * 16 + lrow;
            bool cok = (!NBOUND) || (gc < Nlim);
            float bv = cok ? bias[gc] : 0.f;
            #pragma unroll
            for (int rix = 0; rix < 4; ++rix) {
                if (cok) {
                    float v = acc[m][n][rix] + bv;
                    size_t o = (size_t)(gr0 + rix) * ldc + gc;
                    if (OUTBF16) ((bf16*)Cv)[o] = (bf16)v;
                    else         ((float*)Cv)[o] = v;
                }
            }
        }
    }
}

// ---------------------------------------------------------------------------
// Elementwise gates for one timestep.
// ps: [B, 5H] fp32 (b_state already added). pi_t: [B, 6H] bf16 (b_in added).
// cst: [B,H] fp32 in/out. hout: h_t as bf16 (feeds next step + final GEMM).
// ---------------------------------------------------------------------------
__device__ __forceinline__ float sigmoidf_(float x) { return 1.f / (1.f + __expf(-x)); }
__device__ __forceinline__ float tanhf_(float x)    { return 1.f - 2.f / (__expf(2.f * x) + 1.f); }

__global__ __launch_bounds__(256)
void gates_k(const float* __restrict__ ps, const bf16* __restrict__ pi_t,
             float* __restrict__ cst, const float* __restrict__ dmask,
             bf16* __restrict__ hout)
{
    int j  = blockIdx.x * 256 + threadIdx.x;   // [0, B*H)
    int b  = j >> 10;
    int hh = j & 1023;
    const float* psb = ps + (size_t)b * 5120 + hh;
    const bf16*  pib = pi_t + (size_t)b * 6144 + hh;

    float p0 = (float)pib[0]    + psb[0];
    float p1 = (float)pib[1024] + psb[1024];
    float p2 = (float)pib[2048] + psb[2048];
    float p3 = (float)pib[3072] + psb[3072];
    float p4 = (float)pib[4096] + psb[4096];
    float p5 = (float)pib[5120];

    float ig = sigmoidf_(p0);
    float fg = sigmoidf_(p1);
    float mi = tanhf_(p2);
    float og = sigmoidf_(p3);
    float hw = sigmoidf_(p4);

    float cc  = cst[j];
    float mem = ig * mi + fg * cc;
    cst[j] = mem;
    float out = og * tanhf_(mem);
    out = hw * out + (1.f - hw) * p5;
    out *= dmask[j];
    hout[j] = (bf16)out;
}

// ---------------------------------------------------------------------------
// Small init / cast kernels
// ---------------------------------------------------------------------------
__global__ void cast_f2b_k(const float* __restrict__ src, bf16* __restrict__ dst, int n) {
    int i = blockIdx.x * 256 + threadIdx.x;
    if (i < n) dst[i] = (bf16)src[i];
}

// W_out [C,H] -> bf16 [192,H], rows >= C zero-filled
__global__ void cast_wout_k(const float* __restrict__ src, bf16* __restrict__ dst, int Crows) {
    int i = blockIdx.x * 256 + threadIdx.x;    // over 192*1024
    int r = i >> 10;
    dst[i] = (r < Crows) ? (bf16)src[i] : (bf16)0.f;
}

// row-wise cast with K padding: src [rows, klim] fp32 -> dst [rows, kp] bf16
__global__ void cast_pad_k(const float* __restrict__ src, bf16* __restrict__ dst,
                           int klim, int kp) {
    int r = blockIdx.x;
    const float* s = src + (size_t)r * klim;
    bf16* d = dst + (size_t)r * kp;
    for (int c = threadIdx.x; c < kp; c += 256)
        d[c] = (c < klim) ? (bf16)s[c] : (bf16)0.f;
}

__global__ void init_state_k(const float* __restrict__ c0, const float* __restrict__ h0,
                             float* __restrict__ cst, bf16* __restrict__ hs0) {
    int i = blockIdx.x * 256 + threadIdx.x;
    cst[i] = c0[i];
    hs0[i] = (bf16)h0[i];
}

// ---------------------------------------------------------------------------
extern "C" void kernel_launch(void* const* d_in, const int* in_sizes, int n_in,
                              void* d_out, int out_size, void* d_ws, size_t ws_size,
                              hipStream_t stream)
{
    const float* x       = (const float*)d_in[0];
    const float* h0      = (const float*)d_in[1];
    const float* c0      = (const float*)d_in[2];
    const float* dmask   = (const float*)d_in[3];
    const float* W_in    = (const float*)d_in[4];
    const float* b_in    = (const float*)d_in[5];
    const float* W_state = (const float*)d_in[6];
    const float* b_state = (const float*)d_in[7];
    const float* W_out   = (const float*)d_in[8];
    const float* b_out   = (const float*)d_in[9];

    constexpr int T = 32, B = 256, DIN = 4196, H = 1024, C = 151;
    constexpr int M  = T * B;       // 8192
    constexpr int KP = 4224;        // DIN padded to multiple of 32
    constexpr int N6 = 6 * H;       // 6144
    constexpr int N5 = 5 * H;       // 5120

    size_t off = 0;
    auto carve = [&](size_t bytes) -> void* {
        void* p = (char*)d_ws + off;
        off += (bytes + 255) & ~(size_t)255;
        return p;
    };
    bf16*  pi  = (bf16*) carve((size_t)M * N6 * 2);        // 100.7 MB
    bf16*  wsb = (bf16*) carve((size_t)N5 * H * 2);        //  10.5 MB
    bf16*  wob = (bf16*) carve((size_t)192 * H * 2);       //   0.4 MB
    bf16*  hs  = (bf16*) carve((size_t)(T + 1) * B * H * 2); // 17.3 MB (slot t = h_{t-1})
    float* cst = (float*)carve((size_t)B * H * 4);         //   1.0 MB
    float* ps  = (float*)carve((size_t)B * N5 * 4);        //   5.2 MB
    size_t base_need = off;

    bf16 *xb = nullptr, *wb = nullptr;
    bool precast = (ws_size >= base_need + (size_t)M * KP * 2 + (size_t)N6 * KP * 2 + 1024);
    if (precast) {
        xb = (bf16*)carve((size_t)M * KP * 2);             // 69.2 MB
        wb = (bf16*)carve((size_t)N6 * KP * 2);            // 51.9 MB
    }
    if (ws_size < base_need) {
        fprintf(stderr, "kernel_launch: ws too small (%zu < %zu)\n", ws_size, base_need);
        return;
    }

    // ---- init / weight casts ----
    hipLaunchKernelGGL(cast_f2b_k, dim3((N5 * H + 255) / 256), dim3(256), 0, stream,
                       W_state, wsb, N5 * H);
    hipLaunchKernelGGL(cast_wout_k, dim3(192 * H / 256), dim3(256), 0, stream, W_out, wob, C);
    hipLaunchKernelGGL(init_state_k, dim3(B * H / 256), dim3(256), 0, stream, c0, h0, cst, hs);

    // ---- big input-projection GEMM: pi = bf16(X @ W_in^T + b_in) ----
    if (precast) {
        hipLaunchKernelGGL(cast_pad_k, dim3(M),  dim3(256), 0, stream, x,    xb, DIN, KP);
        hipLaunchKernelGGL(cast_pad_k, dim3(N6), dim3(256), 0, stream, W_in, wb, DIN, KP);
        hipLaunchKernelGGL((gemm_k<128, 128, false, true, false>),
                           dim3(N6 / 128, M / 128), dim3(256), 0, stream,
                           xb, wb, pi, b_in, KP, KP, KP, KP, N6, N6);
    } else {
        hipLaunchKernelGGL((gemm_k<128, 128, true, true, false>),
                           dim3(N6 / 128, M / 128), dim3(256), 0, stream,
                           x, W_in, pi, b_in, KP, DIN, DIN, DIN, N6, N6);
    }

    // ---- recurrence: 32 sequential (GEMM + gates) ----
    for (int t = 0; t < T; ++t) {
        hipLaunchKernelGGL((gemm_k<64, 64, false, false, false>),
                           dim3(N5 / 64, B / 64), dim3(256), 0, stream,
                           hs + (size_t)t * B * H, wsb, ps, b_state,
                           H, H, H, H, N5, N5);
        hipLaunchKernelGGL(gates_k, dim3(B * H / 256), dim3(256), 0, stream,
                           ps, pi + (size_t)t * B * N6, cst, dmask,
                           hs + (size_t)(t + 1) * B * H);
    }

    // ---- output projection: logits = hs @ W_out^T + b_out (N bounded to 151) ----
    hipLaunchKernelGGL((gemm_k<128, 64, false, false, true>),
                       dim3(192 / 64, M / 128), dim3(256), 0, stream,
                       hs + (size_t)B * H, wob, (float*)d_out, b_out,
                       H, H, H, H, C, C);
}